// Round 6
// baseline (15194.379 us; speedup 1.0000x reference)
//
#include <hip/hip_runtime.h>
#include <hip/hip_bf16.h>

#define NB 16
#define SB 2048
#define DB 256
#define EB 512
#define LB 4
#define NPAR 4
#define NSEG_CAP 1024
#define GRID_MAIN 512

typedef __bf16 bf16x8 __attribute__((ext_vector_type(8)));
typedef float  f32x4  __attribute__((ext_vector_type(4)));

// ---------------- workspace layout (bytes) ----------------
#define OFF_XBF   0ull
#define SZ_XBF    (16ull*2048*256*2)          // x as bf16
#define OFF_W     (OFF_XBF + SZ_XBF)          // uniform [l][2048][1024] bf16
#define SZ_W      (4ull*2048*1024*2)
#define OFF_BIAS  (OFF_W + SZ_W)              // 4*2048 f32 (b_ih+b_hh)
#define OFF_H     (OFF_BIAS + 4ull*2048*4)    // [l][par(4)][seg][e] bf16
#define SZ_H      (4ull*NPAR*NSEG_CAP*EB*2)
#define OFF_C     (OFF_H + SZ_H)              // [l][seg][e] f32
#define SZ_C      (4ull*NSEG_CAP*EB*4)
#define OFF_SROW   (OFF_C + SZ_C)
#define OFF_SSTART (OFF_SROW  + 4ull*NSEG_CAP)
#define OFF_SLEN   (OFF_SSTART + 4ull*NSEG_CAP)
#define OFF_SSLOT  (OFF_SLEN  + 4ull*NSEG_CAP)
#define OFF_XOFF   (OFF_SSLOT + 4ull*NSEG_CAP) // xoff[seg] = row*SB+start
#define OFF_ACT   (OFF_XOFF + 4ull*NSEG_CAP)  // active[r], 2048 ints
#define OFF_META  (OFF_ACT + 4ull*2048)       // [0]=NSEG [1]=maxlen
#define OFF_FLAGS (OFF_META + 256ull)         // [l][r][128] u32
#define SZ_FLAGS  (4ull*2048*128*4)

__device__ __forceinline__ unsigned short f2bf(float f) {
  union { float f; unsigned u; } v; v.f = f;
  unsigned r = v.u + 0x7FFFu + ((v.u >> 16) & 1u);
  return (unsigned short)(r >> 16);
}
__device__ __forceinline__ float sigf(float x) {
  x = fminf(30.f, fmaxf(-30.f, x));
  return 1.f / (1.f + __expf(-x));
}
__device__ __forceinline__ float tanhx(float x) {
  x = fminf(15.f, fmaxf(-15.f, x));
  float e = __expf(-2.f * x);
  return (1.f - e) / (1.f + e);
}

// ---------------- kernel 1: conversions + zeroing ----------------
__global__ void k_conv(const float* __restrict__ x, const float* __restrict__ wih0,
                       const float* __restrict__ wihr, const float* __restrict__ whh,
                       const float* __restrict__ bih, const float* __restrict__ bhh,
                       float* __restrict__ dout, int out_size, char* __restrict__ ws) {
  long long gid = (long long)blockIdx.x * blockDim.x + threadIdx.x;
  long long stride = (long long)gridDim.x * blockDim.x;
  for (long long i = gid; i < out_size; i += stride) dout[i] = 0.f;
  unsigned* hz = (unsigned*)(ws + OFF_H);
  long long hcw = (long long)(SZ_H + SZ_C) / 4;
  for (long long i = gid; i < hcw; i += stride) hz[i] = 0u;
  unsigned* fz = (unsigned*)(ws + OFF_FLAGS);
  for (long long i = gid; i < (long long)(SZ_FLAGS / 4); i += stride) fz[i] = 0u;
  float* bias = (float*)(ws + OFF_BIAS);
  for (long long i = gid; i < 4 * 2048; i += stride) bias[i] = bih[i] + bhh[i];
  // uniform weights [l][2048 n][1024 k] bf16; l==0: k<256 = W_ih0, 256..511 = 0, 512+ = W_hh[0]
  unsigned short* wbf = (unsigned short*)(ws + OFF_W);
  for (long long i = gid; i < 4ll * 2048 * 1024; i += stride) {
    int l = (int)(i >> 21);
    int rem = (int)(i & ((1 << 21) - 1));
    int n = rem >> 10, k = rem & 1023;
    float v;
    if (l == 0)
      v = (k < 256) ? wih0[n * 256 + k]
        : (k < 512) ? 0.f
        : whh[(long long)n * 512 + (k - 512)];
    else
      v = (k < 512) ? wihr[((long long)(l - 1) * 2048 + n) * 512 + k]
                    : whh[((long long)l * 2048 + n) * 512 + (k - 512)];
    wbf[i] = f2bf(v);
  }
  unsigned short* xb = (unsigned short*)(ws + OFF_XBF);
  for (long long i = gid; i < (long long)NB * SB * DB; i += stride) xb[i] = f2bf(x[i]);
}

// ---------------- kernel 2: segmentation + sort (1 block) ----------------
__global__ void k_seg(const void* __restrict__ maskp, char* __restrict__ ws,
                      float* __restrict__ dout, int Sp) {
  __shared__ unsigned bits[NB][64];
  __shared__ int hist[2050];
  __shared__ int sufx[2051];
  __shared__ int part[256];
  __shared__ unsigned metapk[NSEG_CAP];
  __shared__ int slotar[NSEG_CAP];
  __shared__ int rowcnt[NB];
  __shared__ int flagbits, nseg, maxlen;
  int tid = threadIdx.x;
  if (tid == 0) { flagbits = 0; nseg = 0; maxlen = 0; }
  for (int i = tid; i < 2050; i += 256) hist[i] = 0;
  __syncthreads();
  const unsigned* mw = (const unsigned*)maskp;
  int fb = 0;
  for (int i = tid; i < 8192; i += 256) {
    unsigned w = mw[i];
    if (w == 0x3F800000u) fb |= 2;
    if (w == 0x3FF00000u) fb |= 4;
    if (w & 0xFFFFFF00u) fb |= 1;
    if ((i & 1) && w) fb |= 8;
  }
  if (fb) atomicOr(&flagbits, fb);
  __syncthreads();
  int f = flagbits;
  int kind = (f & 4) ? 3 : (f & 2) ? 2 : (f & 1) ? 0 : (f & 8) ? 1 : 3;
  for (int w = tid; w < NB * 64; w += 256) {
    int row = w >> 6, j = w & 63;
    unsigned b = 0;
    int t0 = j * 32;
    for (int z = 0; z < 32; ++z) {
      long long idx = (long long)row * SB + t0 + z;
      bool sep;
      if (kind == 0)      sep = ((const unsigned char*)maskp)[idx] != 0;
      else if (kind == 1) sep = ((const int*)maskp)[idx] != 0;
      else if (kind == 2) sep = ((const float*)maskp)[idx] != 0.f;
      else                sep = ((const unsigned long long*)maskp)[idx] != 0ull;
      b |= (sep ? 1u : 0u) << z;
    }
    bits[row][j] = b;
  }
  __syncthreads();
  if (tid < NB) {
    int row = tid, i = 0, cnt = 0;
    for (int w = 0; w < 64; ++w) {
      unsigned b = bits[row][w];
      while (b) {
        int z = __ffs(b) - 1; b &= b - 1;
        int t = w * 32 + z;
        if (i != t) {
          int len = t - i;
          int idx = atomicAdd(&nseg, 1);
          if (idx < NSEG_CAP) { metapk[idx] = ((unsigned)row << 23) | ((unsigned)i << 12) | (unsigned)len; slotar[idx] = cnt; }
          atomicAdd(&hist[len], 1); atomicMax(&maxlen, len);
          cnt++;
        }
        i = t + 1;
      }
    }
    if (i != SB) {
      int len = SB - i;
      int idx = atomicAdd(&nseg, 1);
      if (idx < NSEG_CAP) { metapk[idx] = ((unsigned)row << 23) | ((unsigned)i << 12) | (unsigned)len; slotar[idx] = cnt; }
      atomicAdd(&hist[len], 1); atomicMax(&maxlen, len);
      cnt++;
    }
    rowcnt[row] = cnt;
  }
  __syncthreads();
  {
    int lo = tid * 9, hi = lo + 9; if (hi > 2050) hi = 2050;
    int s = 0;
    for (int k = lo; k < hi; ++k) s += hist[k];
    part[tid] = s;
  }
  __syncthreads();
  {
    int tail = 0;
    for (int t2 = tid + 1; t2 < 256; ++t2) tail += part[t2];
    int lo = tid * 9, hi = lo + 9; if (hi > 2050) hi = 2050;
    int run = tail;
    for (int k = hi - 1; k >= lo; --k) { run += hist[k]; sufx[k] = run; }
  }
  __syncthreads();
  int* act = (int*)(ws + OFF_ACT);
  for (int r = tid; r < 2048; r += 256) act[r] = sufx[r + 1];
  for (int i = tid; i < 2050; i += 256) hist[i] = 0;
  __syncthreads();
  int NSEG = nseg < NSEG_CAP ? nseg : NSEG_CAP;
  int* srow = (int*)(ws + OFF_SROW);
  int* sstart = (int*)(ws + OFF_SSTART);
  int* slen = (int*)(ws + OFF_SLEN);
  int* sslot = (int*)(ws + OFF_SSLOT);
  int* xoff = (int*)(ws + OFF_XOFF);
  for (int i = tid; i < NSEG; i += 256) {
    unsigned m = metapk[i];
    int len = m & 0xFFF, st = (m >> 12) & 0x7FF, row = (int)(m >> 23);
    int pos = sufx[len + 1] + atomicAdd(&hist[len], 1);
    srow[pos] = row; sstart[pos] = st; slen[pos] = len; sslot[pos] = slotar[i];
    xoff[pos] = row * SB + st;
  }
  int* meta = (int*)(ws + OFF_META);
  if (tid == 0) { meta[0] = NSEG; meta[1] = maxlen; }
  __syncthreads();
  float* omask = dout + (long long)NB * Sp * EB;
  for (int i = tid; i < NB * Sp; i += 256) {
    int row = i / Sp, slot = i % Sp;
    omask[i] = (slot < rowcnt[row]) ? 0.f : 1.f;
  }
}

// ---------------- kernel 3: persistent dataflow LSTM pipeline ----------------
// block = (layer l, 4 e-values) -> 16 W-rows, W in LDS [kgroup][row][8] (conflict-free b128).
// 8 waves = (mf: m-frag 0..3, kq: K-half). 512 blocks = 2/CU, all co-resident.
__global__ void __launch_bounds__(512, 4)
k_main(char* __restrict__ ws, float* __restrict__ dout, int Sp) {
  __shared__ __align__(16) __bf16 wlds[128][16][8];  // 32 KB
  __shared__ float glds[2][64][17];                  // K-half partial exchange
  __shared__ float bias_s[16];
  __shared__ short act_s[2048];
  __shared__ unsigned short xoff_s[NSEG_CAP];
  const int tid = threadIdx.x;
  const int l = blockIdx.x >> 7, wb = blockIdx.x & 127, e0 = wb << 2;
  const int wave = tid >> 6, lane = tid & 63;
  const int mf = wave & 3, kq = wave >> 2;
  const int l15 = lane & 15, lq = lane >> 4;
  const char* wsb = ws;

  {
    const int* act = (const int*)(ws + OFF_ACT);
    for (int i = tid; i < 2048; i += 512) act_s[i] = (short)act[i];
    const int* xoff = (const int*)(ws + OFF_XOFF);
    for (int i = tid; i < NSEG_CAP; i += 512) xoff_s[i] = (unsigned short)xoff[i];
    if (tid < 16) bias_s[tid] =
        ((const float*)(ws + OFF_BIAS))[l * 2048 + (tid >> 2) * 512 + e0 + (tid & 3)];
    // W slice -> LDS: [kg][rho][8], rho = g*4+e
    int rho = tid & 15, g = rho >> 2, e = rho & 3;
    const unsigned short* wsrc = (const unsigned short*)(wsb + OFF_W)
        + ((size_t)(l * 2048 + g * 512 + e0 + e)) * 1024;
    int kg0 = (tid >> 4) * 4;
    #pragma unroll
    for (int j = 0; j < 4; ++j)
      *(bf16x8*)&wlds[kg0 + j][rho][0] = *(const bf16x8*)(wsrc + (size_t)(kg0 + j) * 8);
  }
  const int maxlen = ((const int*)(ws + OFF_META))[1];
  __syncthreads();

  const int* srow  = (const int*)(ws + OFF_SROW);
  const int* slen  = (const int*)(ws + OFF_SLEN);
  const int* sslot = (const int*)(ws + OFF_SSLOT);
  unsigned* flags = (unsigned*)(ws + OFF_FLAGS);

  for (int r = 0; r < maxlen; ++r) {
    // ---- dataflow wait: producer (l-1,r), recurrence (l,r-1), back-pressure (l+1,r-4) ----
    const bool nA = (l > 0), nB = (r > 0), nC = (l < 3) && (r >= 4);
    if (wave == 0 && (nA | nB | nC)) {
      const unsigned* pa = flags + ((((l - 1) * 2048 + r) << 7) + lane);
      const unsigned* pb = flags + (((l * 2048 + (r - 1)) << 7) + lane);
      const unsigned* pc = flags + ((((l + 1) * 2048 + (r - 4)) << 7) + lane);
      while (true) {
        unsigned ok = 1;
        if (nA) ok &= (__hip_atomic_load(pa, __ATOMIC_RELAXED, __HIP_MEMORY_SCOPE_AGENT) != 0)
                    & (__hip_atomic_load(pa + 64, __ATOMIC_RELAXED, __HIP_MEMORY_SCOPE_AGENT) != 0);
        if (nB) ok &= (__hip_atomic_load(pb, __ATOMIC_RELAXED, __HIP_MEMORY_SCOPE_AGENT) != 0)
                    & (__hip_atomic_load(pb + 64, __ATOMIC_RELAXED, __HIP_MEMORY_SCOPE_AGENT) != 0);
        if (nC) ok &= (__hip_atomic_load(pc, __ATOMIC_RELAXED, __HIP_MEMORY_SCOPE_AGENT) != 0)
                    & (__hip_atomic_load(pc + 64, __ATOMIC_RELAXED, __HIP_MEMORY_SCOPE_AGENT) != 0);
        if (__all((int)ok)) break;
        __builtin_amdgcn_s_sleep(2);
      }
      __threadfence();   // acquire
    }
    __syncthreads();

    const int M = act_s[r];
    const int nmch = (M + 63) >> 6;
    for (int mch = 0; mch < nmch; ++mch) {
      const int segbase = mch << 6;
      int Mv = M - segbase; if (Mv > 64) Mv = 64;
      // ---- per-lane A base: rows = this wave's 16 segs, k-half = kq ----
      const int m_l = (mf << 4) + l15;
      const int sg = segbase + ((m_l < Mv) ? m_l : 0);
      const char* ap;
      if (kq == 0) {
        if (l == 0) {
          ap = wsb + OFF_XBF + (((size_t)((int)xoff_s[sg] + r)) * DB + lq * 8) * 2;
        } else {
          ap = wsb + OFF_H + ((size_t)((((l - 1) * NPAR + (r & 3)) * NSEG_CAP) + sg) * EB + lq * 8) * 2;
        }
      } else {
        ap = wsb + OFF_H + ((size_t)(((l * NPAR + ((r - 1) & 3)) * NSEG_CAP) + sg) * EB + lq * 8) * 2;
      }
      // ---- early prefetch for epilogue (tid<256: one (m,e) cell each) ----
      const int em = tid >> 2, ee = tid & 3;
      float cold = 0.f; int slenv = 0, srowv = 0, sslotv = 0;
      float* cptr = (float*)(ws + OFF_C + ((size_t)(l * NSEG_CAP + segbase + em) * EB + e0 + ee) * 4);
      if (tid < 256) {
        cold = *cptr;
        if (l == 3) {
          int sg2 = segbase + em;
          slenv = slen[sg2]; srowv = srow[sg2]; sslotv = sslot[sg2];
        }
      }
      // ---- MFMA: 16 steps of 16x16x32, A from global, B from LDS ----
      f32x4 acc = {0.f, 0.f, 0.f, 0.f};
      #pragma unroll
      for (int t = 0; t < 16; ++t) {
        bf16x8 a = *(const bf16x8*)(ap + t * 64);
        bf16x8 b = *(const bf16x8*)&wlds[(kq << 6) + (t << 2) + lq][l15][0];
        acc = __builtin_amdgcn_mfma_f32_16x16x32_bf16(a, b, acc, 0, 0, 0);
      }
      // ---- partial exchange: D row = lq*4+reg (m within frag), col = l15 (rho) ----
      #pragma unroll
      for (int reg = 0; reg < 4; ++reg)
        glds[kq][(mf << 4) + (lq << 2) + reg][l15] = acc[reg];
      __syncthreads();
      // ---- epilogue: 64 m x 4 e cells over first 256 threads ----
      if (tid < 256 && em < Mv) {
        int sg2 = segbase + em;
        float gi = glds[0][em][ee]      + glds[1][em][ee]      + bias_s[ee];
        float gf = glds[0][em][4 + ee]  + glds[1][em][4 + ee]  + bias_s[4 + ee];
        float gg = glds[0][em][8 + ee]  + glds[1][em][8 + ee]  + bias_s[8 + ee];
        float go = glds[0][em][12 + ee] + glds[1][em][12 + ee] + bias_s[12 + ee];
        float cnew = sigf(gf) * cold + sigf(gi) * tanhx(gg);
        float hnew = sigf(go) * tanhx(cnew);
        *cptr = cnew;
        *(unsigned short*)(ws + OFF_H +
            ((size_t)(((l * NPAR + (r & 3)) * NSEG_CAP) + sg2) * EB + e0 + ee) * 2) = f2bf(hnew);
        if (l == 3 && r == slenv - 1) {
          if (sslotv < Sp) dout[(((long long)srowv * Sp + sslotv) << 9) + e0 + ee] = hnew;
        }
      }
      __syncthreads();
    }
    // ---- release: L2 writeback + one agent release store ----
    if (tid == 0) {
      __threadfence();
      __hip_atomic_store(flags + (((l * 2048 + r) << 7) + wb), 1u,
                         __ATOMIC_RELEASE, __HIP_MEMORY_SCOPE_AGENT);
    }
  }
}

extern "C" void kernel_launch(void* const* d_in, const int* in_sizes, int n_in,
                              void* d_out, int out_size, void* d_ws, size_t ws_size,
                              hipStream_t stream) {
  const float* x    = (const float*)d_in[0];
  const void*  mask = d_in[1];
  const float* wih0 = (const float*)d_in[2];
  const float* wihr = (const float*)d_in[3];
  const float* whh  = (const float*)d_in[4];
  const float* bih  = (const float*)d_in[5];
  const float* bhh  = (const float*)d_in[6];
  float* out = (float*)d_out;
  char* ws = (char*)d_ws;
  int Sp = out_size / (NB * (EB + 1));   // out = N*Sp*E  +  N*Sp mask

  k_conv<<<dim3(2048), dim3(256), 0, stream>>>(x, wih0, wihr, whh, bih, bhh, out, out_size, ws);
  k_seg<<<dim3(1), dim3(256), 0, stream>>>(mask, ws, out, Sp);
  k_main<<<dim3(GRID_MAIN), dim3(512), 0, stream>>>(ws, out, Sp);
}

// Round 7
// 10938.144 us; speedup vs baseline: 1.3891x; 1.3891x over previous
//
#include <hip/hip_runtime.h>
#include <hip/hip_bf16.h>

#define NB 16
#define SB 2048
#define DB 256
#define EB 512
#define LB 4
#define NPAR 4
#define NSEG_CAP 1024
#define GRID_MAIN 128

typedef __bf16 bf16x8 __attribute__((ext_vector_type(8)));
typedef float  f32x4  __attribute__((ext_vector_type(4)));

// ---------------- workspace layout (bytes) ----------------
#define OFF_XBF   0ull
#define SZ_XBF    (16ull*2048*256*2)          // x as bf16
#define OFF_W     (OFF_XBF + SZ_XBF)          // uniform [l][2048][1024] bf16
#define SZ_W      (4ull*2048*1024*2)
#define OFF_BIAS  (OFF_W + SZ_W)              // 4*2048 f32 (b_ih+b_hh)
#define OFF_H     (OFF_BIAS + 4ull*2048*4)    // [l][par(4)][seg][e] bf16
#define SZ_H      (4ull*NPAR*NSEG_CAP*EB*2)
#define OFF_C     (OFF_H + SZ_H)              // [l][seg][e] f32
#define SZ_C      (4ull*NSEG_CAP*EB*4)
#define OFF_SROW   (OFF_C + SZ_C)
#define OFF_SSTART (OFF_SROW  + 4ull*NSEG_CAP)
#define OFF_SLEN   (OFF_SSTART + 4ull*NSEG_CAP)
#define OFF_SSLOT  (OFF_SLEN  + 4ull*NSEG_CAP)
#define OFF_XOFF   (OFF_SSLOT + 4ull*NSEG_CAP) // xoff[seg] = row*SB+start
#define OFF_ACT   (OFF_XOFF + 4ull*NSEG_CAP)  // active[r], 2048 ints
#define OFF_META  (OFF_ACT + 4ull*2048)       // [0]=NSEG [1]=maxlen
#define OFF_FLAGS (OFF_META + 256ull)         // [l][r][32] u32 (padded alloc)
#define SZ_FLAGS  (4ull*2048*128*4)

__device__ __forceinline__ unsigned short f2bf(float f) {
  union { float f; unsigned u; } v; v.f = f;
  unsigned r = v.u + 0x7FFFu + ((v.u >> 16) & 1u);
  return (unsigned short)(r >> 16);
}
__device__ __forceinline__ float sigf(float x) {
  x = fminf(30.f, fmaxf(-30.f, x));
  return 1.f / (1.f + __expf(-x));
}
__device__ __forceinline__ float tanhx(float x) {
  x = fminf(15.f, fmaxf(-15.f, x));
  float e = __expf(-2.f * x);
  return (1.f - e) / (1.f + e);
}

// ---------------- kernel 1: conversions + zeroing ----------------
__global__ void k_conv(const float* __restrict__ x, const float* __restrict__ wih0,
                       const float* __restrict__ wihr, const float* __restrict__ whh,
                       const float* __restrict__ bih, const float* __restrict__ bhh,
                       float* __restrict__ dout, int out_size, char* __restrict__ ws) {
  long long gid = (long long)blockIdx.x * blockDim.x + threadIdx.x;
  long long stride = (long long)gridDim.x * blockDim.x;
  for (long long i = gid; i < out_size; i += stride) dout[i] = 0.f;
  unsigned* hz = (unsigned*)(ws + OFF_H);
  long long hcw = (long long)(SZ_H + SZ_C) / 4;
  for (long long i = gid; i < hcw; i += stride) hz[i] = 0u;
  unsigned* fz = (unsigned*)(ws + OFF_FLAGS);
  for (long long i = gid; i < (long long)(SZ_FLAGS / 4); i += stride) fz[i] = 0u;
  float* bias = (float*)(ws + OFF_BIAS);
  for (long long i = gid; i < 4 * 2048; i += stride) bias[i] = bih[i] + bhh[i];
  // uniform weights [l][2048 n][1024 k] bf16; l==0: k<256 = W_ih0, 256..511 = 0, 512+ = W_hh[0]
  unsigned short* wbf = (unsigned short*)(ws + OFF_W);
  for (long long i = gid; i < 4ll * 2048 * 1024; i += stride) {
    int l = (int)(i >> 21);
    int rem = (int)(i & ((1 << 21) - 1));
    int n = rem >> 10, k = rem & 1023;
    float v;
    if (l == 0)
      v = (k < 256) ? wih0[n * 256 + k]
        : (k < 512) ? 0.f
        : whh[(long long)n * 512 + (k - 512)];
    else
      v = (k < 512) ? wihr[((long long)(l - 1) * 2048 + n) * 512 + k]
                    : whh[((long long)l * 2048 + n) * 512 + (k - 512)];
    wbf[i] = f2bf(v);
  }
  unsigned short* xb = (unsigned short*)(ws + OFF_XBF);
  for (long long i = gid; i < (long long)NB * SB * DB; i += stride) xb[i] = f2bf(x[i]);
}

// ---------------- kernel 2: segmentation + sort (1 block) ----------------
__global__ void k_seg(const void* __restrict__ maskp, char* __restrict__ ws,
                      float* __restrict__ dout, int Sp) {
  __shared__ unsigned bits[NB][64];
  __shared__ int hist[2050];
  __shared__ int sufx[2051];
  __shared__ int part[256];
  __shared__ unsigned metapk[NSEG_CAP];
  __shared__ int slotar[NSEG_CAP];
  __shared__ int rowcnt[NB];
  __shared__ int flagbits, nseg, maxlen;
  int tid = threadIdx.x;
  if (tid == 0) { flagbits = 0; nseg = 0; maxlen = 0; }
  for (int i = tid; i < 2050; i += 256) hist[i] = 0;
  __syncthreads();
  const unsigned* mw = (const unsigned*)maskp;
  int fb = 0;
  for (int i = tid; i < 8192; i += 256) {
    unsigned w = mw[i];
    if (w == 0x3F800000u) fb |= 2;
    if (w == 0x3FF00000u) fb |= 4;
    if (w & 0xFFFFFF00u) fb |= 1;
    if ((i & 1) && w) fb |= 8;
  }
  if (fb) atomicOr(&flagbits, fb);
  __syncthreads();
  int f = flagbits;
  int kind = (f & 4) ? 3 : (f & 2) ? 2 : (f & 1) ? 0 : (f & 8) ? 1 : 3;
  for (int w = tid; w < NB * 64; w += 256) {
    int row = w >> 6, j = w & 63;
    unsigned b = 0;
    int t0 = j * 32;
    for (int z = 0; z < 32; ++z) {
      long long idx = (long long)row * SB + t0 + z;
      bool sep;
      if (kind == 0)      sep = ((const unsigned char*)maskp)[idx] != 0;
      else if (kind == 1) sep = ((const int*)maskp)[idx] != 0;
      else if (kind == 2) sep = ((const float*)maskp)[idx] != 0.f;
      else                sep = ((const unsigned long long*)maskp)[idx] != 0ull;
      b |= (sep ? 1u : 0u) << z;
    }
    bits[row][j] = b;
  }
  __syncthreads();
  if (tid < NB) {
    int row = tid, i = 0, cnt = 0;
    for (int w = 0; w < 64; ++w) {
      unsigned b = bits[row][w];
      while (b) {
        int z = __ffs(b) - 1; b &= b - 1;
        int t = w * 32 + z;
        if (i != t) {
          int len = t - i;
          int idx = atomicAdd(&nseg, 1);
          if (idx < NSEG_CAP) { metapk[idx] = ((unsigned)row << 23) | ((unsigned)i << 12) | (unsigned)len; slotar[idx] = cnt; }
          atomicAdd(&hist[len], 1); atomicMax(&maxlen, len);
          cnt++;
        }
        i = t + 1;
      }
    }
    if (i != SB) {
      int len = SB - i;
      int idx = atomicAdd(&nseg, 1);
      if (idx < NSEG_CAP) { metapk[idx] = ((unsigned)row << 23) | ((unsigned)i << 12) | (unsigned)len; slotar[idx] = cnt; }
      atomicAdd(&hist[len], 1); atomicMax(&maxlen, len);
      cnt++;
    }
    rowcnt[row] = cnt;
  }
  __syncthreads();
  {
    int lo = tid * 9, hi = lo + 9; if (hi > 2050) hi = 2050;
    int s = 0;
    for (int k = lo; k < hi; ++k) s += hist[k];
    part[tid] = s;
  }
  __syncthreads();
  {
    int tail = 0;
    for (int t2 = tid + 1; t2 < 256; ++t2) tail += part[t2];
    int lo = tid * 9, hi = lo + 9; if (hi > 2050) hi = 2050;
    int run = tail;
    for (int k = hi - 1; k >= lo; --k) { run += hist[k]; sufx[k] = run; }
  }
  __syncthreads();
  int* act = (int*)(ws + OFF_ACT);
  for (int r = tid; r < 2048; r += 256) act[r] = sufx[r + 1];
  for (int i = tid; i < 2050; i += 256) hist[i] = 0;
  __syncthreads();
  int NSEG = nseg < NSEG_CAP ? nseg : NSEG_CAP;
  int* srow = (int*)(ws + OFF_SROW);
  int* sstart = (int*)(ws + OFF_SSTART);
  int* slen = (int*)(ws + OFF_SLEN);
  int* sslot = (int*)(ws + OFF_SSLOT);
  int* xoff = (int*)(ws + OFF_XOFF);
  for (int i = tid; i < NSEG; i += 256) {
    unsigned m = metapk[i];
    int len = m & 0xFFF, st = (m >> 12) & 0x7FF, row = (int)(m >> 23);
    int pos = sufx[len + 1] + atomicAdd(&hist[len], 1);
    srow[pos] = row; sstart[pos] = st; slen[pos] = len; sslot[pos] = slotar[i];
    xoff[pos] = row * SB + st;
  }
  int* meta = (int*)(ws + OFF_META);
  if (tid == 0) { meta[0] = NSEG; meta[1] = maxlen; }
  __syncthreads();
  float* omask = dout + (long long)NB * Sp * EB;
  for (int i = tid; i < NB * Sp; i += 256) {
    int row = i / Sp, slot = i % Sp;
    omask[i] = (slot < rowcnt[row]) ? 0.f : 1.f;
  }
}

// ---------------- kernel 3: persistent dataflow LSTM pipeline ----------------
// 128 blocks = (layer l, 16 e-values). 8 waves = (nq: gate 0..3, kh: K-half).
// W register-stationary at 64 VGPR/wave (16 frags); all static metadata in LDS.
__global__ void __launch_bounds__(512, 1)
k_main(char* __restrict__ ws, float* __restrict__ dout, int Sp) {
  __shared__ float glds[64][68];               // gate exchange, 17.4 KB
  __shared__ unsigned segpk_s[NSEG_CAP];       // slen | sslot<<16 | srow<<28
  __shared__ unsigned short xoff_s[NSEG_CAP];
  __shared__ unsigned short act_s[2048];
  __shared__ float bias_s[64];
  const int tid = threadIdx.x;
  const int l = blockIdx.x >> 5, wb = blockIdx.x & 31, e0 = wb << 4;
  const int wave = tid >> 6, lane = tid & 63;
  const int nq = wave & 3, kh = wave >> 2;
  const int l15 = lane & 15, lq = lane >> 4;
  const char* wsb = ws;

  // ---- LDS preload (survives per-stage L2 invalidations) ----
  {
    const int* act = (const int*)(ws + OFF_ACT);
    for (int i = tid; i < 2048; i += 512) act_s[i] = (unsigned short)act[i];
    const int* xoff = (const int*)(ws + OFF_XOFF);
    const int* srow = (const int*)(ws + OFF_SROW);
    const int* slen = (const int*)(ws + OFF_SLEN);
    const int* sslot = (const int*)(ws + OFF_SSLOT);
    for (int i = tid; i < NSEG_CAP; i += 512) {
      xoff_s[i] = (unsigned short)xoff[i];
      segpk_s[i] = ((unsigned)slen[i] & 0xFFFu) | (((unsigned)sslot[i] & 0xFFFu) << 16)
                 | (((unsigned)srow[i] & 0xFu) << 28);
    }
    if (tid < 64) bias_s[tid] =
        ((const float*)(ws + OFF_BIAS))[l * 2048 + (tid >> 4) * 512 + e0 + (tid & 15)];
  }
  const int maxlen = ((const int*)(ws + OFF_META))[1];

  // ---- W fragments: wave (gate nq, e row l15), K-half kh -> 16 frags = 64 VGPR ----
  bf16x8 breg[16];
  {
    const char* wrow = wsb + OFF_W + ((size_t)(l * 2048 + nq * 512 + e0 + l15)) * 2048;
    #pragma unroll
    for (int t = 0; t < 16; ++t)
      breg[t] = *(const bf16x8*)(wrow + (size_t)(kh * 512 + t * 32 + lq * 8) * 2);
  }
  __syncthreads();

  unsigned* flags = (unsigned*)(ws + OFF_FLAGS);

  for (int r = 0; r < maxlen; ++r) {
    // ---- dataflow wait: producer (l-1,r), recurrence (l,r-1), back-pressure (l+1,r-4) ----
    const bool nA = (l > 0), nB = (r > 0), nC = (l < 3) && (r >= 4);
    if (wave == 0 && (nA | nB | nC)) {
      int li = lane & 31;
      while (true) {
        unsigned ok = 1;
        if (nA) ok &= (__hip_atomic_load(flags + ((((l - 1) * 2048 + r) << 5) + li),
                                         __ATOMIC_RELAXED, __HIP_MEMORY_SCOPE_AGENT) != 0);
        if (nB) ok &= (__hip_atomic_load(flags + (((l * 2048 + (r - 1)) << 5) + li),
                                         __ATOMIC_RELAXED, __HIP_MEMORY_SCOPE_AGENT) != 0);
        if (nC) ok &= (__hip_atomic_load(flags + ((((l + 1) * 2048 + (r - 4)) << 5) + li),
                                         __ATOMIC_RELAXED, __HIP_MEMORY_SCOPE_AGENT) != 0);
        if (__all((int)ok)) break;
        __builtin_amdgcn_s_sleep(2);
      }
      __threadfence();   // acquire (L1/L2 inv) — LDS-held data unaffected
    }
    __syncthreads();

    const int M = act_s[r];
    const int nmch = (M + 63) >> 6;
    for (int mch = 0; mch < nmch; ++mch) {
      const int segbase = mch << 6;
      int Mv = M - segbase; if (Mv > 64) Mv = 64;
      // ---- A bases: 4 m-frags, rows = this wave's segs, k-half = kh ----
      const char* ap[4];
      #pragma unroll
      for (int mf = 0; mf < 4; ++mf) {
        int m_l = (mf << 4) + l15;
        int sg = segbase + ((m_l < Mv) ? m_l : 0);
        const char* base;
        if (kh == 0) {
          if (l == 0)
            base = wsb + OFF_XBF + (((size_t)((int)xoff_s[sg] + r)) * DB) * 2;
          else
            base = wsb + OFF_H + ((size_t)((((l - 1) * NPAR + (r & 3)) * NSEG_CAP) + sg) * EB) * 2;
        } else {
          base = wsb + OFF_H + ((size_t)(((l * NPAR + ((r - 1) & 3)) * NSEG_CAP) + sg) * EB) * 2;
        }
        ap[mf] = base + lq * 16;
      }
      // ---- c prefetch (2 cells/thread; overlaps MFMA) ----
      const int em = tid >> 4, ee = tid & 15;
      float* cp0 = (float*)(ws + OFF_C + ((size_t)(l * NSEG_CAP + segbase + em) * EB + e0 + ee) * 4);
      float* cp1 = (float*)(ws + OFF_C + ((size_t)(l * NSEG_CAP + segbase + em + 32) * EB + e0 + ee) * 4);
      float cold0 = *cp0, cold1 = *cp1;
      // ---- MFMA: 16 steps x 4 m-frags, B register-stationary ----
      f32x4 acc[4];
      #pragma unroll
      for (int mf = 0; mf < 4; ++mf) acc[mf] = (f32x4){0.f, 0.f, 0.f, 0.f};
      #pragma unroll
      for (int t = 0; t < 16; ++t) {
        #pragma unroll
        for (int mf = 0; mf < 4; ++mf) {
          bf16x8 a = *(const bf16x8*)(ap[mf] + t * 64);
          acc[mf] = __builtin_amdgcn_mfma_f32_16x16x32_bf16(a, breg[t], acc[mf], 0, 0, 0);
        }
      }
      // ---- two-phase K-half merge in glds: D row m = lq*4+reg, col n = nq*16+l15 ----
      if (kh == 0) {
        #pragma unroll
        for (int mf = 0; mf < 4; ++mf)
          #pragma unroll
          for (int reg = 0; reg < 4; ++reg)
            glds[(mf << 4) + (lq << 2) + reg][(nq << 4) + l15] = acc[mf][reg];
      }
      __syncthreads();
      if (kh == 1) {
        #pragma unroll
        for (int mf = 0; mf < 4; ++mf)
          #pragma unroll
          for (int reg = 0; reg < 4; ++reg)
            glds[(mf << 4) + (lq << 2) + reg][(nq << 4) + l15] += acc[mf][reg];
      }
      __syncthreads();
      // ---- epilogue: 64 m x 16 e cells, 2 per thread ----
      #pragma unroll
      for (int q = 0; q < 2; ++q) {
        int m = em + (q << 5);
        float cold = q ? cold1 : cold0;
        float* cptr = q ? cp1 : cp0;
        if (m < Mv) {
          int sg2 = segbase + m;
          float gi = glds[m][ee]      + bias_s[ee];
          float gf = glds[m][16 + ee] + bias_s[16 + ee];
          float gg = glds[m][32 + ee] + bias_s[32 + ee];
          float go = glds[m][48 + ee] + bias_s[48 + ee];
          float cnew = sigf(gf) * cold + sigf(gi) * tanhx(gg);
          float hnew = sigf(go) * tanhx(cnew);
          *cptr = cnew;
          *(unsigned short*)(ws + OFF_H +
              ((size_t)(((l * NPAR + (r & 3)) * NSEG_CAP) + sg2) * EB + e0 + ee) * 2) = f2bf(hnew);
          if (l == 3) {
            unsigned pk = segpk_s[sg2];
            if (r == (int)(pk & 0xFFFu) - 1) {
              int sl = (int)((pk >> 16) & 0xFFFu), rw = (int)(pk >> 28);
              if (sl < Sp) dout[(((long long)rw * Sp + sl) << 9) + e0 + ee] = hnew;
            }
          }
        }
      }
      __syncthreads();
    }
    // ---- release: L2 writeback + one agent release store ----
    if (tid == 0) {
      __threadfence();
      __hip_atomic_store(flags + (((l * 2048 + r) << 5) + wb), 1u,
                         __ATOMIC_RELEASE, __HIP_MEMORY_SCOPE_AGENT);
    }
  }
}

extern "C" void kernel_launch(void* const* d_in, const int* in_sizes, int n_in,
                              void* d_out, int out_size, void* d_ws, size_t ws_size,
                              hipStream_t stream) {
  const float* x    = (const float*)d_in[0];
  const void*  mask = d_in[1];
  const float* wih0 = (const float*)d_in[2];
  const float* wihr = (const float*)d_in[3];
  const float* whh  = (const float*)d_in[4];
  const float* bih  = (const float*)d_in[5];
  const float* bhh  = (const float*)d_in[6];
  float* out = (float*)d_out;
  char* ws = (char*)d_ws;
  int Sp = out_size / (NB * (EB + 1));   // out = N*Sp*E  +  N*Sp mask

  k_conv<<<dim3(2048), dim3(256), 0, stream>>>(x, wih0, wihr, whh, bih, bhh, out, out_size, ws);
  k_seg<<<dim3(1), dim3(256), 0, stream>>>(mask, ws, out, Sp);
  k_main<<<dim3(GRID_MAIN), dim3(512), 0, stream>>>(ws, out, Sp);
}

// Round 8
// 10827.702 us; speedup vs baseline: 1.4033x; 1.0102x over previous
//
#include <hip/hip_runtime.h>
#include <hip/hip_bf16.h>

#define NB 16
#define SB 2048
#define DB 256
#define EB 512
#define LB 4
#define NPAR 4
#define NSEG_CAP 1024
#define GRID_MAIN 128

typedef __bf16 bf16x8 __attribute__((ext_vector_type(8)));
typedef float  f32x4  __attribute__((ext_vector_type(4)));

// ---------------- workspace layout (bytes) ----------------
#define OFF_XBF   0ull
#define SZ_XBF    (16ull*2048*256*2)          // x as bf16
#define OFF_W     (OFF_XBF + SZ_XBF)          // uniform [l][2048][1024] bf16
#define SZ_W      (4ull*2048*1024*2)
#define OFF_BIAS  (OFF_W + SZ_W)              // 4*2048 f32 (b_ih+b_hh)
#define OFF_H     (OFF_BIAS + 4ull*2048*4)    // [l][par(4)][seg][e] bf16
#define SZ_H      (4ull*NPAR*NSEG_CAP*EB*2)
#define OFF_C     (OFF_H + SZ_H)              // [l][seg][e] f32
#define SZ_C      (4ull*NSEG_CAP*EB*4)
#define OFF_SROW   (OFF_C + SZ_C)
#define OFF_SSTART (OFF_SROW  + 4ull*NSEG_CAP)
#define OFF_SLEN   (OFF_SSTART + 4ull*NSEG_CAP)
#define OFF_SSLOT  (OFF_SLEN  + 4ull*NSEG_CAP)
#define OFF_XOFF   (OFF_SSLOT + 4ull*NSEG_CAP) // xoff[seg] = row*SB+start
#define OFF_ACT   (OFF_XOFF + 4ull*NSEG_CAP)  // active[r], 2048 ints
#define OFF_META  (OFF_ACT + 4ull*2048)       // [0]=NSEG [1]=maxlen
#define OFF_FLAGS (OFF_META + 256ull)         // [l][r][32] u32 (padded alloc)
#define SZ_FLAGS  (4ull*2048*128*4)

__device__ __forceinline__ unsigned short f2bf(float f) {
  union { float f; unsigned u; } v; v.f = f;
  unsigned r = v.u + 0x7FFFu + ((v.u >> 16) & 1u);
  return (unsigned short)(r >> 16);
}
__device__ __forceinline__ float sigf(float x) {
  x = fminf(30.f, fmaxf(-30.f, x));
  return 1.f / (1.f + __expf(-x));
}
__device__ __forceinline__ float tanhx(float x) {
  x = fminf(15.f, fmaxf(-15.f, x));
  float e = __expf(-2.f * x);
  return (1.f - e) / (1.f + e);
}

// ---------------- kernel 1: conversions + zeroing ----------------
__global__ void k_conv(const float* __restrict__ x, const float* __restrict__ wih0,
                       const float* __restrict__ wihr, const float* __restrict__ whh,
                       const float* __restrict__ bih, const float* __restrict__ bhh,
                       float* __restrict__ dout, int out_size, char* __restrict__ ws) {
  long long gid = (long long)blockIdx.x * blockDim.x + threadIdx.x;
  long long stride = (long long)gridDim.x * blockDim.x;
  for (long long i = gid; i < out_size; i += stride) dout[i] = 0.f;
  unsigned* hz = (unsigned*)(ws + OFF_H);
  long long hcw = (long long)(SZ_H + SZ_C) / 4;
  for (long long i = gid; i < hcw; i += stride) hz[i] = 0u;
  unsigned* fz = (unsigned*)(ws + OFF_FLAGS);
  for (long long i = gid; i < (long long)(SZ_FLAGS / 4); i += stride) fz[i] = 0u;
  float* bias = (float*)(ws + OFF_BIAS);
  for (long long i = gid; i < 4 * 2048; i += stride) bias[i] = bih[i] + bhh[i];
  // uniform weights [l][2048 n][1024 k] bf16; l==0: k<256 = W_ih0, 256..511 = 0, 512+ = W_hh[0]
  unsigned short* wbf = (unsigned short*)(ws + OFF_W);
  for (long long i = gid; i < 4ll * 2048 * 1024; i += stride) {
    int l = (int)(i >> 21);
    int rem = (int)(i & ((1 << 21) - 1));
    int n = rem >> 10, k = rem & 1023;
    float v;
    if (l == 0)
      v = (k < 256) ? wih0[n * 256 + k]
        : (k < 512) ? 0.f
        : whh[(long long)n * 512 + (k - 512)];
    else
      v = (k < 512) ? wihr[((long long)(l - 1) * 2048 + n) * 512 + k]
                    : whh[((long long)l * 2048 + n) * 512 + (k - 512)];
    wbf[i] = f2bf(v);
  }
  unsigned short* xb = (unsigned short*)(ws + OFF_XBF);
  for (long long i = gid; i < (long long)NB * SB * DB; i += stride) xb[i] = f2bf(x[i]);
}

// ---------------- kernel 2: segmentation + sort (1 block) ----------------
__global__ void k_seg(const void* __restrict__ maskp, char* __restrict__ ws,
                      float* __restrict__ dout, int Sp) {
  __shared__ unsigned bits[NB][64];
  __shared__ int hist[2050];
  __shared__ int sufx[2051];
  __shared__ int part[256];
  __shared__ unsigned metapk[NSEG_CAP];
  __shared__ int slotar[NSEG_CAP];
  __shared__ int rowcnt[NB];
  __shared__ int flagbits, nseg, maxlen;
  int tid = threadIdx.x;
  if (tid == 0) { flagbits = 0; nseg = 0; maxlen = 0; }
  for (int i = tid; i < 2050; i += 256) hist[i] = 0;
  __syncthreads();
  const unsigned* mw = (const unsigned*)maskp;
  int fb = 0;
  for (int i = tid; i < 8192; i += 256) {
    unsigned w = mw[i];
    if (w == 0x3F800000u) fb |= 2;
    if (w == 0x3FF00000u) fb |= 4;
    if (w & 0xFFFFFF00u) fb |= 1;
    if ((i & 1) && w) fb |= 8;
  }
  if (fb) atomicOr(&flagbits, fb);
  __syncthreads();
  int f = flagbits;
  int kind = (f & 4) ? 3 : (f & 2) ? 2 : (f & 1) ? 0 : (f & 8) ? 1 : 3;
  for (int w = tid; w < NB * 64; w += 256) {
    int row = w >> 6, j = w & 63;
    unsigned b = 0;
    int t0 = j * 32;
    for (int z = 0; z < 32; ++z) {
      long long idx = (long long)row * SB + t0 + z;
      bool sep;
      if (kind == 0)      sep = ((const unsigned char*)maskp)[idx] != 0;
      else if (kind == 1) sep = ((const int*)maskp)[idx] != 0;
      else if (kind == 2) sep = ((const float*)maskp)[idx] != 0.f;
      else                sep = ((const unsigned long long*)maskp)[idx] != 0ull;
      b |= (sep ? 1u : 0u) << z;
    }
    bits[row][j] = b;
  }
  __syncthreads();
  if (tid < NB) {
    int row = tid, i = 0, cnt = 0;
    for (int w = 0; w < 64; ++w) {
      unsigned b = bits[row][w];
      while (b) {
        int z = __ffs(b) - 1; b &= b - 1;
        int t = w * 32 + z;
        if (i != t) {
          int len = t - i;
          int idx = atomicAdd(&nseg, 1);
          if (idx < NSEG_CAP) { metapk[idx] = ((unsigned)row << 23) | ((unsigned)i << 12) | (unsigned)len; slotar[idx] = cnt; }
          atomicAdd(&hist[len], 1); atomicMax(&maxlen, len);
          cnt++;
        }
        i = t + 1;
      }
    }
    if (i != SB) {
      int len = SB - i;
      int idx = atomicAdd(&nseg, 1);
      if (idx < NSEG_CAP) { metapk[idx] = ((unsigned)row << 23) | ((unsigned)i << 12) | (unsigned)len; slotar[idx] = cnt; }
      atomicAdd(&hist[len], 1); atomicMax(&maxlen, len);
      cnt++;
    }
    rowcnt[row] = cnt;
  }
  __syncthreads();
  {
    int lo = tid * 9, hi = lo + 9; if (hi > 2050) hi = 2050;
    int s = 0;
    for (int k = lo; k < hi; ++k) s += hist[k];
    part[tid] = s;
  }
  __syncthreads();
  {
    int tail = 0;
    for (int t2 = tid + 1; t2 < 256; ++t2) tail += part[t2];
    int lo = tid * 9, hi = lo + 9; if (hi > 2050) hi = 2050;
    int run = tail;
    for (int k = hi - 1; k >= lo; --k) { run += hist[k]; sufx[k] = run; }
  }
  __syncthreads();
  int* act = (int*)(ws + OFF_ACT);
  for (int r = tid; r < 2048; r += 256) act[r] = sufx[r + 1];
  for (int i = tid; i < 2050; i += 256) hist[i] = 0;
  __syncthreads();
  int NSEG = nseg < NSEG_CAP ? nseg : NSEG_CAP;
  int* srow = (int*)(ws + OFF_SROW);
  int* sstart = (int*)(ws + OFF_SSTART);
  int* slen = (int*)(ws + OFF_SLEN);
  int* sslot = (int*)(ws + OFF_SSLOT);
  int* xoff = (int*)(ws + OFF_XOFF);
  for (int i = tid; i < NSEG; i += 256) {
    unsigned m = metapk[i];
    int len = m & 0xFFF, st = (m >> 12) & 0x7FF, row = (int)(m >> 23);
    int pos = sufx[len + 1] + atomicAdd(&hist[len], 1);
    srow[pos] = row; sstart[pos] = st; slen[pos] = len; sslot[pos] = slotar[i];
    xoff[pos] = row * SB + st;
  }
  int* meta = (int*)(ws + OFF_META);
  if (tid == 0) { meta[0] = NSEG; meta[1] = maxlen; }
  __syncthreads();
  float* omask = dout + (long long)NB * Sp * EB;
  for (int i = tid; i < NB * Sp; i += 256) {
    int row = i / Sp, slot = i % Sp;
    omask[i] = (slot < rowcnt[row]) ? 0.f : 1.f;
  }
}

// ---------------- kernel 3: persistent dataflow LSTM pipeline ----------------
// 128 blocks = (layer l = bid&3 for XCD locality, 16 e-values). W slice (64 rows x 1024 k)
// lives in 128 KB dynamic LDS -> immune to the per-stage fence invalidation AND to the
// register allocator. 8 waves = (nq: gate 0..3, mh: m-half), full-K accumulation.
__global__ void __launch_bounds__(512, 1)
k_main(char* __restrict__ ws, float* __restrict__ dout, int Sp) {
  extern __shared__ __align__(16) char dynlds[];
  __bf16 (*wlds)[64][8] = (__bf16 (*)[64][8])dynlds;   // [kg 128][row 64][8]
  __shared__ float glds[64][68];               // gate exchange
  __shared__ unsigned segpk_s[NSEG_CAP];       // slen | sslot<<16 | srow<<28
  __shared__ unsigned short xoff_s[NSEG_CAP];
  __shared__ unsigned short act_s[2048];
  __shared__ float bias_s[64];
  const int tid = threadIdx.x;
  const int l = blockIdx.x & 3, wb = blockIdx.x >> 2, e0 = wb << 4;
  const int wave = tid >> 6, lane = tid & 63;
  const int nq = wave & 3, mh = wave >> 2;
  const int l15 = lane & 15, lq = lane >> 4;
  const char* wsb = ws;

  // ---- LDS preload (survives per-stage L2 invalidations) ----
  {
    const int* act = (const int*)(ws + OFF_ACT);
    for (int i = tid; i < 2048; i += 512) act_s[i] = (unsigned short)act[i];
    const int* xoff = (const int*)(ws + OFF_XOFF);
    const int* srow = (const int*)(ws + OFF_SROW);
    const int* slen = (const int*)(ws + OFF_SLEN);
    const int* sslot = (const int*)(ws + OFF_SSLOT);
    for (int i = tid; i < NSEG_CAP; i += 512) {
      xoff_s[i] = (unsigned short)xoff[i];
      segpk_s[i] = ((unsigned)slen[i] & 0xFFFu) | (((unsigned)sslot[i] & 0xFFFu) << 16)
                 | (((unsigned)srow[i] & 0xFu) << 28);
    }
    if (tid < 64) bias_s[tid] =
        ((const float*)(ws + OFF_BIAS))[l * 2048 + (tid >> 4) * 512 + e0 + (tid & 15)];
    // W slice -> dynamic LDS: [kg][row][8], row = g*16 + e
    for (int i = tid; i < 128 * 64; i += 512) {
      int kg = i >> 6, row = i & 63;
      int g = row >> 4, e = row & 15;
      const char* src = wsb + OFF_W +
          (((size_t)(l * 2048 + g * 512 + e0 + e)) * 1024 + (size_t)kg * 8) * 2;
      *(bf16x8*)&wlds[kg][row][0] = *(const bf16x8*)src;
    }
  }
  const int maxlen = ((const int*)(ws + OFF_META))[1];
  __syncthreads();

  unsigned* flags = (unsigned*)(ws + OFF_FLAGS);

  for (int r = 0; r < maxlen; ++r) {
    // ---- dataflow wait: producer (l-1,r), recurrence (l,r-1), back-pressure (l+1,r-4) ----
    const bool nA = (l > 0), nB = (r > 0), nC = (l < 3) && (r >= 4);
    if (wave == 0 && (nA | nB | nC)) {
      int li = lane & 31;
      while (true) {
        unsigned ok = 1;
        if (nA) ok &= (__hip_atomic_load(flags + ((((l - 1) * 2048 + r) << 5) + li),
                                         __ATOMIC_RELAXED, __HIP_MEMORY_SCOPE_AGENT) != 0);
        if (nB) ok &= (__hip_atomic_load(flags + (((l * 2048 + (r - 1)) << 5) + li),
                                         __ATOMIC_RELAXED, __HIP_MEMORY_SCOPE_AGENT) != 0);
        if (nC) ok &= (__hip_atomic_load(flags + ((((l + 1) * 2048 + (r - 4)) << 5) + li),
                                         __ATOMIC_RELAXED, __HIP_MEMORY_SCOPE_AGENT) != 0);
        if (__all((int)ok)) break;
        __builtin_amdgcn_s_sleep(2);
      }
      __threadfence();   // acquire (L1/L2 inv) — LDS-held W/metadata unaffected
    }
    __syncthreads();

    const int M = act_s[r];
    const int nmch = (M + 63) >> 6;
    for (int mch = 0; mch < nmch; ++mch) {
      const int segbase = mch << 6;
      int Mv = M - segbase; if (Mv > 64) Mv = 64;
      // ---- A bases: 2 m-frags/wave; lo = input side (k<512), hi = recurrent (k>=512) ----
      const char *aplo[2], *aphi[2];
      #pragma unroll
      for (int mf = 0; mf < 2; ++mf) {
        int m_l = (mh << 5) + (mf << 4) + l15;
        int sg = segbase + ((m_l < Mv) ? m_l : 0);
        const char* lo;
        if (l == 0)
          lo = wsb + OFF_XBF + (((size_t)((int)xoff_s[sg] + r)) * DB) * 2;
        else
          lo = wsb + OFF_H + ((size_t)((((l - 1) * NPAR + (r & 3)) * NSEG_CAP) + sg) * EB) * 2;
        aplo[mf] = lo + lq * 16;
        aphi[mf] = wsb + OFF_H +
            ((size_t)(((l * NPAR + ((r - 1) & 3)) * NSEG_CAP) + sg) * EB) * 2 + lq * 16;
      }
      // ---- c prefetch (2 cells/thread; overlaps MFMA, consumed in epilogue) ----
      const int em = tid >> 4, ee = tid & 15;
      float* cp0 = (float*)(ws + OFF_C + ((size_t)(l * NSEG_CAP + segbase + em) * EB + e0 + ee) * 4);
      float* cp1 = (float*)(ws + OFF_C + ((size_t)(l * NSEG_CAP + segbase + em + 32) * EB + e0 + ee) * 4);
      float cold0 = *cp0, cold1 = *cp1;
      // ---- MFMA: 32 k-steps, A global, B from LDS (linear ds_read_b128) ----
      f32x4 acc[2];
      acc[0] = (f32x4){0.f, 0.f, 0.f, 0.f};
      acc[1] = (f32x4){0.f, 0.f, 0.f, 0.f};
      #pragma unroll
      for (int t = 0; t < 16; ++t) {
        bf16x8 b = *(const bf16x8*)&wlds[(t << 2) + lq][(nq << 4) + l15][0];
        #pragma unroll
        for (int mf = 0; mf < 2; ++mf) {
          bf16x8 a = *(const bf16x8*)(aplo[mf] + t * 64);
          acc[mf] = __builtin_amdgcn_mfma_f32_16x16x32_bf16(a, b, acc[mf], 0, 0, 0);
        }
      }
      #pragma unroll
      for (int t = 16; t < 32; ++t) {
        bf16x8 b = *(const bf16x8*)&wlds[(t << 2) + lq][(nq << 4) + l15][0];
        #pragma unroll
        for (int mf = 0; mf < 2; ++mf) {
          bf16x8 a = *(const bf16x8*)(aphi[mf] + (t - 16) * 64);
          acc[mf] = __builtin_amdgcn_mfma_f32_16x16x32_bf16(a, b, acc[mf], 0, 0, 0);
        }
      }
      // ---- glds: D row m = mh*32 + mf*16 + lq*4 + reg, col = nq*16 + l15 ----
      #pragma unroll
      for (int mf = 0; mf < 2; ++mf)
        #pragma unroll
        for (int reg = 0; reg < 4; ++reg)
          glds[(mh << 5) + (mf << 4) + (lq << 2) + reg][(nq << 4) + l15] = acc[mf][reg];
      __syncthreads();
      // ---- epilogue: 64 m x 16 e cells, 2 per thread ----
      #pragma unroll
      for (int q = 0; q < 2; ++q) {
        int m = em + (q << 5);
        float cold = q ? cold1 : cold0;
        float* cptr = q ? cp1 : cp0;
        if (m < Mv) {
          int sg2 = segbase + m;
          float gi = glds[m][ee]      + bias_s[ee];
          float gf = glds[m][16 + ee] + bias_s[16 + ee];
          float gg = glds[m][32 + ee] + bias_s[32 + ee];
          float go = glds[m][48 + ee] + bias_s[48 + ee];
          float cnew = sigf(gf) * cold + sigf(gi) * tanhx(gg);
          float hnew = sigf(go) * tanhx(cnew);
          *cptr = cnew;
          *(unsigned short*)(ws + OFF_H +
              ((size_t)(((l * NPAR + (r & 3)) * NSEG_CAP) + sg2) * EB + e0 + ee) * 2) = f2bf(hnew);
          if (l == 3) {
            unsigned pk = segpk_s[sg2];
            if (r == (int)(pk & 0xFFFu) - 1) {
              int sl = (int)((pk >> 16) & 0xFFFu), rw = (int)(pk >> 28);
              if (sl < Sp) dout[(((long long)rw * Sp + sl) << 9) + e0 + ee] = hnew;
            }
          }
        }
      }
      __syncthreads();
    }
    // ---- release: L2 writeback + one agent release store ----
    if (tid == 0) {
      __threadfence();
      __hip_atomic_store(flags + (((l * 2048 + r) << 5) + wb), 1u,
                         __ATOMIC_RELEASE, __HIP_MEMORY_SCOPE_AGENT);
    }
  }
}

extern "C" void kernel_launch(void* const* d_in, const int* in_sizes, int n_in,
                              void* d_out, int out_size, void* d_ws, size_t ws_size,
                              hipStream_t stream) {
  const float* x    = (const float*)d_in[0];
  const void*  mask = d_in[1];
  const float* wih0 = (const float*)d_in[2];
  const float* wihr = (const float*)d_in[3];
  const float* whh  = (const float*)d_in[4];
  const float* bih  = (const float*)d_in[5];
  const float* bhh  = (const float*)d_in[6];
  float* out = (float*)d_out;
  char* ws = (char*)d_ws;
  int Sp = out_size / (NB * (EB + 1));   // out = N*Sp*E  +  N*Sp mask

  (void)hipFuncSetAttribute((const void*)k_main,
                            hipFuncAttributeMaxDynamicSharedMemorySize, 131072);
  k_conv<<<dim3(2048), dim3(256), 0, stream>>>(x, wih0, wihr, whh, bih, bhh, out, out_size, ws);
  k_seg<<<dim3(1), dim3(256), 0, stream>>>(mask, ws, out, Sp);
  k_main<<<dim3(GRID_MAIN), dim3(512), 131072, stream>>>(ws, out, Sp);
}

// Round 9
// 10802.536 us; speedup vs baseline: 1.4066x; 1.0023x over previous
//
#include <hip/hip_runtime.h>
#include <hip/hip_bf16.h>

#define NB 16
#define SB 2048
#define DB 256
#define EB 512
#define LB 4
#define NPAR 4
#define NSEG_CAP 1024
#define GRID_MAIN 128

typedef __bf16 bf16x8 __attribute__((ext_vector_type(8)));
typedef float  f32x4  __attribute__((ext_vector_type(4)));

// ---------------- workspace layout (bytes) ----------------
#define OFF_XBF   0ull
#define SZ_XBF    (16ull*2048*256*2)          // x as bf16
#define OFF_W     (OFF_XBF + SZ_XBF)          // uniform [l][2048][1024] bf16
#define SZ_W      (4ull*2048*1024*2)
#define OFF_BIAS  (OFF_W + SZ_W)              // 4*2048 f32 (b_ih+b_hh)
#define OFF_H     (OFF_BIAS + 4ull*2048*4)    // [l][par(4)][seg][e] bf16
#define SZ_H      (4ull*NPAR*NSEG_CAP*EB*2)
#define OFF_C     (OFF_H + SZ_H)              // [l][seg][e] f32
#define SZ_C      (4ull*NSEG_CAP*EB*4)
#define OFF_SROW   (OFF_C + SZ_C)
#define OFF_SSTART (OFF_SROW  + 4ull*NSEG_CAP)
#define OFF_SLEN   (OFF_SSTART + 4ull*NSEG_CAP)
#define OFF_SSLOT  (OFF_SLEN  + 4ull*NSEG_CAP)
#define OFF_XOFF   (OFF_SSLOT + 4ull*NSEG_CAP) // xoff[seg] = row*SB+start
#define OFF_ACT   (OFF_XOFF + 4ull*NSEG_CAP)  // active[r], 2048 ints
#define OFF_META  (OFF_ACT + 4ull*2048)       // [0]=NSEG [1]=maxlen
#define OFF_FLAGS (OFF_META + 256ull)         // [l][r][32] u32 (padded alloc)
#define SZ_FLAGS  (4ull*2048*128*4)

__device__ __forceinline__ unsigned short f2bf(float f) {
  union { float f; unsigned u; } v; v.f = f;
  unsigned r = v.u + 0x7FFFu + ((v.u >> 16) & 1u);
  return (unsigned short)(r >> 16);
}
__device__ __forceinline__ float sigf(float x) {
  x = fminf(30.f, fmaxf(-30.f, x));
  return 1.f / (1.f + __expf(-x));
}
__device__ __forceinline__ float tanhx(float x) {
  x = fminf(15.f, fmaxf(-15.f, x));
  float e = __expf(-2.f * x);
  return (1.f - e) / (1.f + e);
}

// ---------------- kernel 1: conversions + zeroing ----------------
__global__ void k_conv(const float* __restrict__ x, const float* __restrict__ wih0,
                       const float* __restrict__ wihr, const float* __restrict__ whh,
                       const float* __restrict__ bih, const float* __restrict__ bhh,
                       float* __restrict__ dout, int out_size, char* __restrict__ ws) {
  long long gid = (long long)blockIdx.x * blockDim.x + threadIdx.x;
  long long stride = (long long)gridDim.x * blockDim.x;
  for (long long i = gid; i < out_size; i += stride) dout[i] = 0.f;
  unsigned* hz = (unsigned*)(ws + OFF_H);
  long long hcw = (long long)(SZ_H + SZ_C) / 4;
  for (long long i = gid; i < hcw; i += stride) hz[i] = 0u;
  unsigned* fz = (unsigned*)(ws + OFF_FLAGS);
  for (long long i = gid; i < (long long)(SZ_FLAGS / 4); i += stride) fz[i] = 0u;
  float* bias = (float*)(ws + OFF_BIAS);
  for (long long i = gid; i < 4 * 2048; i += stride) bias[i] = bih[i] + bhh[i];
  // uniform weights [l][2048 n][1024 k] bf16; l==0: k<256 = W_ih0, 256..511 = 0, 512+ = W_hh[0]
  unsigned short* wbf = (unsigned short*)(ws + OFF_W);
  for (long long i = gid; i < 4ll * 2048 * 1024; i += stride) {
    int l = (int)(i >> 21);
    int rem = (int)(i & ((1 << 21) - 1));
    int n = rem >> 10, k = rem & 1023;
    float v;
    if (l == 0)
      v = (k < 256) ? wih0[n * 256 + k]
        : (k < 512) ? 0.f
        : whh[(long long)n * 512 + (k - 512)];
    else
      v = (k < 512) ? wihr[((long long)(l - 1) * 2048 + n) * 512 + k]
                    : whh[((long long)l * 2048 + n) * 512 + (k - 512)];
    wbf[i] = f2bf(v);
  }
  unsigned short* xb = (unsigned short*)(ws + OFF_XBF);
  for (long long i = gid; i < (long long)NB * SB * DB; i += stride) xb[i] = f2bf(x[i]);
}

// ---------------- kernel 2: segmentation + sort (1 block) ----------------
__global__ void k_seg(const void* __restrict__ maskp, char* __restrict__ ws,
                      float* __restrict__ dout, int Sp) {
  __shared__ unsigned bits[NB][64];
  __shared__ int hist[2050];
  __shared__ int sufx[2051];
  __shared__ int part[256];
  __shared__ unsigned metapk[NSEG_CAP];
  __shared__ int slotar[NSEG_CAP];
  __shared__ int rowcnt[NB];
  __shared__ int flagbits, nseg, maxlen;
  int tid = threadIdx.x;
  if (tid == 0) { flagbits = 0; nseg = 0; maxlen = 0; }
  for (int i = tid; i < 2050; i += 256) hist[i] = 0;
  __syncthreads();
  const unsigned* mw = (const unsigned*)maskp;
  int fb = 0;
  for (int i = tid; i < 8192; i += 256) {
    unsigned w = mw[i];
    if (w == 0x3F800000u) fb |= 2;
    if (w == 0x3FF00000u) fb |= 4;
    if (w & 0xFFFFFF00u) fb |= 1;
    if ((i & 1) && w) fb |= 8;
  }
  if (fb) atomicOr(&flagbits, fb);
  __syncthreads();
  int f = flagbits;
  int kind = (f & 4) ? 3 : (f & 2) ? 2 : (f & 1) ? 0 : (f & 8) ? 1 : 3;
  for (int w = tid; w < NB * 64; w += 256) {
    int row = w >> 6, j = w & 63;
    unsigned b = 0;
    int t0 = j * 32;
    for (int z = 0; z < 32; ++z) {
      long long idx = (long long)row * SB + t0 + z;
      bool sep;
      if (kind == 0)      sep = ((const unsigned char*)maskp)[idx] != 0;
      else if (kind == 1) sep = ((const int*)maskp)[idx] != 0;
      else if (kind == 2) sep = ((const float*)maskp)[idx] != 0.f;
      else                sep = ((const unsigned long long*)maskp)[idx] != 0ull;
      b |= (sep ? 1u : 0u) << z;
    }
    bits[row][j] = b;
  }
  __syncthreads();
  if (tid < NB) {
    int row = tid, i = 0, cnt = 0;
    for (int w = 0; w < 64; ++w) {
      unsigned b = bits[row][w];
      while (b) {
        int z = __ffs(b) - 1; b &= b - 1;
        int t = w * 32 + z;
        if (i != t) {
          int len = t - i;
          int idx = atomicAdd(&nseg, 1);
          if (idx < NSEG_CAP) { metapk[idx] = ((unsigned)row << 23) | ((unsigned)i << 12) | (unsigned)len; slotar[idx] = cnt; }
          atomicAdd(&hist[len], 1); atomicMax(&maxlen, len);
          cnt++;
        }
        i = t + 1;
      }
    }
    if (i != SB) {
      int len = SB - i;
      int idx = atomicAdd(&nseg, 1);
      if (idx < NSEG_CAP) { metapk[idx] = ((unsigned)row << 23) | ((unsigned)i << 12) | (unsigned)len; slotar[idx] = cnt; }
      atomicAdd(&hist[len], 1); atomicMax(&maxlen, len);
      cnt++;
    }
    rowcnt[row] = cnt;
  }
  __syncthreads();
  {
    int lo = tid * 9, hi = lo + 9; if (hi > 2050) hi = 2050;
    int s = 0;
    for (int k = lo; k < hi; ++k) s += hist[k];
    part[tid] = s;
  }
  __syncthreads();
  {
    int tail = 0;
    for (int t2 = tid + 1; t2 < 256; ++t2) tail += part[t2];
    int lo = tid * 9, hi = lo + 9; if (hi > 2050) hi = 2050;
    int run = tail;
    for (int k = hi - 1; k >= lo; --k) { run += hist[k]; sufx[k] = run; }
  }
  __syncthreads();
  int* act = (int*)(ws + OFF_ACT);
  for (int r = tid; r < 2048; r += 256) act[r] = sufx[r + 1];
  for (int i = tid; i < 2050; i += 256) hist[i] = 0;
  __syncthreads();
  int NSEG = nseg < NSEG_CAP ? nseg : NSEG_CAP;
  int* srow = (int*)(ws + OFF_SROW);
  int* sstart = (int*)(ws + OFF_SSTART);
  int* slen = (int*)(ws + OFF_SLEN);
  int* sslot = (int*)(ws + OFF_SSLOT);
  int* xoff = (int*)(ws + OFF_XOFF);
  for (int i = tid; i < NSEG; i += 256) {
    unsigned m = metapk[i];
    int len = m & 0xFFF, st = (m >> 12) & 0x7FF, row = (int)(m >> 23);
    int pos = sufx[len + 1] + atomicAdd(&hist[len], 1);
    srow[pos] = row; sstart[pos] = st; slen[pos] = len; sslot[pos] = slotar[i];
    xoff[pos] = row * SB + st;
  }
  int* meta = (int*)(ws + OFF_META);
  if (tid == 0) { meta[0] = NSEG; meta[1] = maxlen; }
  __syncthreads();
  float* omask = dout + (long long)NB * Sp * EB;
  for (int i = tid; i < NB * Sp; i += 256) {
    int row = i / Sp, slot = i % Sp;
    omask[i] = (slot < rowcnt[row]) ? 0.f : 1.f;
  }
}

// ---------------- kernel 3: persistent dataflow LSTM pipeline ----------------
// 128 blocks = (layer l = bid&3 for XCD locality, 16 e-values). W slice (64 rows x 1024 k)
// lives in 128 KB dynamic LDS -> immune to the per-stage fence invalidation AND to the
// register allocator. 8 waves = (nq: gate 0..3, mh: m-half), full-K accumulation.
__global__ void __launch_bounds__(512, 1)
k_main(char* __restrict__ ws, float* __restrict__ dout, int Sp) {
  extern __shared__ __align__(16) char dynlds[];
  __bf16 (*wlds)[64][8] = (__bf16 (*)[64][8])dynlds;   // [kg 128][row 64][8]
  __shared__ float glds[64][68];               // gate exchange
  __shared__ unsigned segpk_s[NSEG_CAP];       // slen | sslot<<16 | srow<<28
  __shared__ unsigned short xoff_s[NSEG_CAP];
  __shared__ unsigned short act_s[2048];
  __shared__ float bias_s[64];
  const int tid = threadIdx.x;
  const int l = blockIdx.x & 3, wb = blockIdx.x >> 2, e0 = wb << 4;
  const int wave = tid >> 6, lane = tid & 63;
  const int nq = wave & 3, mh = wave >> 2;
  const int l15 = lane & 15, lq = lane >> 4;
  const char* wsb = ws;

  // ---- LDS preload (survives per-stage L2 invalidations) ----
  {
    const int* act = (const int*)(ws + OFF_ACT);
    for (int i = tid; i < 2048; i += 512) act_s[i] = (unsigned short)act[i];
    const int* xoff = (const int*)(ws + OFF_XOFF);
    const int* srow = (const int*)(ws + OFF_SROW);
    const int* slen = (const int*)(ws + OFF_SLEN);
    const int* sslot = (const int*)(ws + OFF_SSLOT);
    for (int i = tid; i < NSEG_CAP; i += 512) {
      xoff_s[i] = (unsigned short)xoff[i];
      segpk_s[i] = ((unsigned)slen[i] & 0xFFFu) | (((unsigned)sslot[i] & 0xFFFu) << 16)
                 | (((unsigned)srow[i] & 0xFu) << 28);
    }
    if (tid < 64) bias_s[tid] =
        ((const float*)(ws + OFF_BIAS))[l * 2048 + (tid >> 4) * 512 + e0 + (tid & 15)];
    // W slice -> dynamic LDS: [kg][row][8], row = g*16 + e
    for (int i = tid; i < 128 * 64; i += 512) {
      int kg = i >> 6, row = i & 63;
      int g = row >> 4, e = row & 15;
      const char* src = wsb + OFF_W +
          (((size_t)(l * 2048 + g * 512 + e0 + e)) * 1024 + (size_t)kg * 8) * 2;
      *(bf16x8*)&wlds[kg][row][0] = *(const bf16x8*)src;
    }
  }
  const int maxlen = ((const int*)(ws + OFF_META))[1];
  __syncthreads();

  unsigned* flags = (unsigned*)(ws + OFF_FLAGS);

  for (int r = 0; r < maxlen; ++r) {
    // ---- dataflow wait: producer (l-1,r), recurrence (l,r-1), back-pressure (l+1,r-4) ----
    const bool nA = (l > 0), nB = (r > 0), nC = (l < 3) && (r >= 4);
    if (wave == 0 && (nA | nB | nC)) {
      int li = lane & 31;
      while (true) {
        unsigned ok = 1;
        if (nA) ok &= (__hip_atomic_load(flags + ((((l - 1) * 2048 + r) << 5) + li),
                                         __ATOMIC_RELAXED, __HIP_MEMORY_SCOPE_AGENT) != 0);
        if (nB) ok &= (__hip_atomic_load(flags + (((l * 2048 + (r - 1)) << 5) + li),
                                         __ATOMIC_RELAXED, __HIP_MEMORY_SCOPE_AGENT) != 0);
        if (nC) ok &= (__hip_atomic_load(flags + ((((l + 1) * 2048 + (r - 4)) << 5) + li),
                                         __ATOMIC_RELAXED, __HIP_MEMORY_SCOPE_AGENT) != 0);
        if (__all((int)ok)) break;
        __builtin_amdgcn_s_sleep(2);
      }
      __threadfence();   // acquire (L1/L2 inv) — LDS-held W/metadata unaffected
    }
    __syncthreads();

    const int M = act_s[r];
    const int nmch = (M + 63) >> 6;
    for (int mch = 0; mch < nmch; ++mch) {
      const int segbase = mch << 6;
      int Mv = M - segbase; if (Mv > 64) Mv = 64;
      // ---- A bases: 2 m-frags/wave; lo = input side (k<512), hi = recurrent (k>=512) ----
      const char *aplo[2], *aphi[2];
      #pragma unroll
      for (int mf = 0; mf < 2; ++mf) {
        int m_l = (mh << 5) + (mf << 4) + l15;
        int sg = segbase + ((m_l < Mv) ? m_l : 0);
        const char* lo;
        if (l == 0)
          lo = wsb + OFF_XBF + (((size_t)((int)xoff_s[sg] + r)) * DB) * 2;
        else
          lo = wsb + OFF_H + ((size_t)((((l - 1) * NPAR + (r & 3)) * NSEG_CAP) + sg) * EB) * 2;
        aplo[mf] = lo + lq * 16;
        aphi[mf] = wsb + OFF_H +
            ((size_t)(((l * NPAR + ((r - 1) & 3)) * NSEG_CAP) + sg) * EB) * 2 + lq * 16;
      }
      // ---- c prefetch (2 cells/thread; overlaps MFMA, consumed in epilogue) ----
      const int em = tid >> 4, ee = tid & 15;
      float* cp0 = (float*)(ws + OFF_C + ((size_t)(l * NSEG_CAP + segbase + em) * EB + e0 + ee) * 4);
      float* cp1 = (float*)(ws + OFF_C + ((size_t)(l * NSEG_CAP + segbase + em + 32) * EB + e0 + ee) * 4);
      float cold0 = *cp0, cold1 = *cp1;
      // ---- MFMA: 32 k-steps, A global, B from LDS (linear ds_read_b128) ----
      f32x4 acc[2];
      acc[0] = (f32x4){0.f, 0.f, 0.f, 0.f};
      acc[1] = (f32x4){0.f, 0.f, 0.f, 0.f};
      #pragma unroll
      for (int t = 0; t < 16; ++t) {
        bf16x8 b = *(const bf16x8*)&wlds[(t << 2) + lq][(nq << 4) + l15][0];
        #pragma unroll
        for (int mf = 0; mf < 2; ++mf) {
          bf16x8 a = *(const bf16x8*)(aplo[mf] + t * 64);
          acc[mf] = __builtin_amdgcn_mfma_f32_16x16x32_bf16(a, b, acc[mf], 0, 0, 0);
        }
      }
      #pragma unroll
      for (int t = 16; t < 32; ++t) {
        bf16x8 b = *(const bf16x8*)&wlds[(t << 2) + lq][(nq << 4) + l15][0];
        #pragma unroll
        for (int mf = 0; mf < 2; ++mf) {
          bf16x8 a = *(const bf16x8*)(aphi[mf] + (t - 16) * 64);
          acc[mf] = __builtin_amdgcn_mfma_f32_16x16x32_bf16(a, b, acc[mf], 0, 0, 0);
        }
      }
      // ---- glds: D row m = mh*32 + mf*16 + lq*4 + reg, col = nq*16 + l15 ----
      #pragma unroll
      for (int mf = 0; mf < 2; ++mf)
        #pragma unroll
        for (int reg = 0; reg < 4; ++reg)
          glds[(mh << 5) + (mf << 4) + (lq << 2) + reg][(nq << 4) + l15] = acc[mf][reg];
      __syncthreads();
      // ---- epilogue: 64 m x 16 e cells, 2 per thread ----
      #pragma unroll
      for (int q = 0; q < 2; ++q) {
        int m = em + (q << 5);
        float cold = q ? cold1 : cold0;
        float* cptr = q ? cp1 : cp0;
        if (m < Mv) {
          int sg2 = segbase + m;
          float gi = glds[m][ee]      + bias_s[ee];
          float gf = glds[m][16 + ee] + bias_s[16 + ee];
          float gg = glds[m][32 + ee] + bias_s[32 + ee];
          float go = glds[m][48 + ee] + bias_s[48 + ee];
          float cnew = sigf(gf) * cold + sigf(gi) * tanhx(gg);
          float hnew = sigf(go) * tanhx(cnew);
          *cptr = cnew;
          *(unsigned short*)(ws + OFF_H +
              ((size_t)(((l * NPAR + (r & 3)) * NSEG_CAP) + sg2) * EB + e0 + ee) * 2) = f2bf(hnew);
          if (l == 3) {
            unsigned pk = segpk_s[sg2];
            if (r == (int)(pk & 0xFFFu) - 1) {
              int sl = (int)((pk >> 16) & 0xFFFu), rw = (int)(pk >> 28);
              if (sl < Sp) dout[(((long long)rw * Sp + sl) << 9) + e0 + ee] = hnew;
            }
          }
        }
      }
      __syncthreads();
    }
    // ---- release: L2 writeback + one agent release store ----
    if (tid == 0) {
      __threadfence();
      __hip_atomic_store(flags + (((l * 2048 + r) << 5) + wb), 1u,
                         __ATOMIC_RELEASE, __HIP_MEMORY_SCOPE_AGENT);
    }
  }
}

extern "C" void kernel_launch(void* const* d_in, const int* in_sizes, int n_in,
                              void* d_out, int out_size, void* d_ws, size_t ws_size,
                              hipStream_t stream) {
  const float* x    = (const float*)d_in[0];
  const void*  mask = d_in[1];
  const float* wih0 = (const float*)d_in[2];
  const float* wihr = (const float*)d_in[3];
  const float* whh  = (const float*)d_in[4];
  const float* bih  = (const float*)d_in[5];
  const float* bhh  = (const float*)d_in[6];
  float* out = (float*)d_out;
  char* ws = (char*)d_ws;
  int Sp = out_size / (NB * (EB + 1));   // out = N*Sp*E  +  N*Sp mask

  (void)hipFuncSetAttribute((const void*)k_main,
                            hipFuncAttributeMaxDynamicSharedMemorySize, 131072);
  k_conv<<<dim3(2048), dim3(256), 0, stream>>>(x, wih0, wihr, whh, bih, bhh, out, out_size, ws);
  k_seg<<<dim3(1), dim3(256), 0, stream>>>(mask, ws, out, Sp);
  k_main<<<dim3(GRID_MAIN), dim3(512), 131072, stream>>>(ws, out, Sp);
}